// Round 11
// baseline (630.733 us; speedup 1.0000x reference)
//
#include <hip/hip_runtime.h>
#include <cstddef>

#define NN 50000
#define HH 128
#define TT 4
#define EE 150000

typedef __attribute__((ext_vector_type(8))) short bfrag8;
typedef __attribute__((ext_vector_type(4))) float f32x4;
typedef __attribute__((ext_vector_type(8))) unsigned short u16x8;

__device__ __forceinline__ float sigm(float v) { return 1.0f / (1.0f + __expf(-v)); }

__device__ __forceinline__ unsigned short f2b(float f) {
    unsigned int u = __float_as_uint(f);
    u += 0x7fffu + ((u >> 16) & 1u);
    return (unsigned short)(u >> 16);
}
__device__ __forceinline__ float b2f(unsigned short s) {
    return __uint_as_float(((unsigned int)s) << 16);
}

__device__ __forceinline__ void gload_lds16(const void* gp, void* lp) {
    __builtin_amdgcn_global_load_lds(
        (const __attribute__((address_space(1))) unsigned int*)gp,
        (__attribute__((address_space(3))) unsigned int*)lp, 16, 0, 0);
}

// packed bf16x8 (as uint4) -> 8 f32 accumulate: 2 VALU/elem total
__device__ __forceinline__ void acc8(float* a, uint4 v) {
    a[0] += __uint_as_float(v.x << 16);
    a[1] += __uint_as_float(v.x & 0xffff0000u);
    a[2] += __uint_as_float(v.y << 16);
    a[3] += __uint_as_float(v.y & 0xffff0000u);
    a[4] += __uint_as_float(v.z << 16);
    a[5] += __uint_as_float(v.z & 0xffff0000u);
    a[6] += __uint_as_float(v.w << 16);
    a[7] += __uint_as_float(v.w & 0xffff0000u);
}

// ================= bucket build: t-major per-(t,node) buckets =================
__global__ __launch_bounds__(256)
void place_bucket(const int* __restrict__ edges, int* __restrict__ degT,
                  unsigned short* __restrict__ rowsT) {
    int eg = blockIdx.x * 256 + threadIdx.x;
    if (eg >= TT * EE) return;
    int t = eg / EE;
    int src = edges[eg * 2];
    int tgt = edges[eg * 2 + 1];
    int p = atomicAdd(&degT[t * NN + tgt], 1);
    if (p < 32) rowsT[((size_t)t * NN + tgt) * 32 + p] = (unsigned short)src;
}

// ================= setup: degP pack + FRAGMENT-LINEAR weight layouts =================
// FL(W[OC][K])[ocg][kc][lane][e] = W[ocg*16+(lane&15)][kc*32+(lane>>4)*8+e]
__global__ __launch_bounds__(256)
void setup_convert(const float* __restrict__ msg_W,
                   const float* __restrict__ W0ih, const float* __restrict__ W0hh,
                   const float* __restrict__ W1ih, const float* __restrict__ W1hh,
                   const float* __restrict__ b0ih, const float* __restrict__ b0hh,
                   const float* __restrict__ b1ih, const float* __restrict__ b1hh,
                   const float* __restrict__ x, const int* __restrict__ degT,
                   unsigned int* __restrict__ degP,
                   unsigned short* __restrict__ wb, float* __restrict__ biasP,
                   unsigned short* __restrict__ xb, unsigned short* __restrict__ hbA,
                   unsigned short* __restrict__ hbB, float* __restrict__ out) {
    int i = blockIdx.x * 256 + threadIdx.x;
    if (i < NN) {
        unsigned int v0 = degT[i];            if (v0 > 32) v0 = 32;
        unsigned int v1 = degT[NN + i];       if (v1 > 32) v1 = 32;
        unsigned int v2 = degT[2 * NN + i];   if (v2 > 32) v2 = 32;
        unsigned int v3 = degT[3 * NN + i];   if (v3 > 32) v3 = 32;
        degP[i] = v0 | (v1 << 8) | (v2 << 16) | (v3 << 24);
        return;
    }
    i -= NN;
    if (i < 131072) {   // BmFL [2][8 ocg][16 kc][64][8]; k = t*128+h
        int l = i >> 16, r = i & 65535;
        int e = r & 7, lane = (r >> 3) & 63, kc = (r >> 9) & 15, ocg = (r >> 13) & 7;
        int f = ocg * 16 + (lane & 15);
        int k = kc * 32 + (lane >> 4) * 8 + e;
        int t = k >> 7, h = k & 127;
        wb[i] = f2b(msg_W[l * 65536 + t * 16384 + f * 128 + h]);
        return;
    }
    i -= 131072;
    if (i < 65536) {    // WrzFL0 [16 ocg][8 kc][64][8]; ocg<8 r else z; k<128 Wih else Whh
        int e = i & 7, lane = (i >> 3) & 63, kc = (i >> 9) & 7, ocg = (i >> 12) & 15;
        int p = ocg * 16 + (lane & 15);
        int g = p >> 7, gc = p & 127;
        int k = kc * 32 + (lane >> 4) * 8 + e;
        float v = (k < 128) ? W0ih[(g * 128 + gc) * 128 + k] : W0hh[(g * 128 + gc) * 128 + (k - 128)];
        wb[131072 + i] = f2b(v);
        return;
    }
    i -= 65536;
    if (i < 98304) {    // WrzFL1 [16 ocg][12 kc][64][8]; k<256 Wih else Whh
        int e = i & 7, lane = (i >> 3) & 63, rem = i >> 9;
        int kc = rem % 12, ocg = rem / 12;
        int p = ocg * 16 + (lane & 15);
        int g = p >> 7, gc = p & 127;
        int k = kc * 32 + (lane >> 4) * 8 + e;
        float v = (k < 256) ? W1ih[(g * 128 + gc) * 256 + k] : W1hh[(g * 128 + gc) * 128 + (k - 256)];
        wb[196608 + i] = f2b(v);
        return;
    }
    i -= 98304;
    if (i < 16384) {    // WxnFL0 [8][4][64][8]
        int e = i & 7, lane = (i >> 3) & 63, rem = i >> 9;
        int kc = rem & 3, ocg = rem >> 2;
        int gc = ocg * 16 + (lane & 15);
        int k = kc * 32 + (lane >> 4) * 8 + e;
        wb[294912 + i] = f2b(W0ih[(256 + gc) * 128 + k]);
        return;
    }
    i -= 16384;
    if (i < 32768) {    // WxnFL1 [8][8][64][8]
        int e = i & 7, lane = (i >> 3) & 63;
        int kc = (i >> 9) & 7, ocg = (i >> 12) & 7;
        int gc = ocg * 16 + (lane & 15);
        int k = kc * 32 + (lane >> 4) * 8 + e;
        wb[311296 + i] = f2b(W1ih[(256 + gc) * 256 + k]);
        return;
    }
    i -= 32768;
    if (i < 16384) {    // WhnFL0 [8][4][64][8]
        int e = i & 7, lane = (i >> 3) & 63, rem = i >> 9;
        int kc = rem & 3, ocg = rem >> 2;
        int gc = ocg * 16 + (lane & 15);
        int k = kc * 32 + (lane >> 4) * 8 + e;
        wb[344064 + i] = f2b(W0hh[(256 + gc) * 128 + k]);
        return;
    }
    i -= 16384;
    if (i < 16384) {    // WhnFL1 [8][4][64][8]
        int e = i & 7, lane = (i >> 3) & 63, rem = i >> 9;
        int kc = rem & 3, ocg = rem >> 2;
        int gc = ocg * 16 + (lane & 15);
        int k = kc * 32 + (lane >> 4) * 8 + e;
        wb[360448 + i] = f2b(W1hh[(256 + gc) * 128 + k]);
        return;
    }
    i -= 16384;
    if (i < 1024) {     // bias [2][512]
        int l = i >> 9, r = i & 511;
        const float* bi = l ? b1ih : b0ih;
        const float* bh = l ? b1hh : b0hh;
        float v;
        if (r < 256) {
            int g = r >> 7, gc = r & 127;
            v = bi[g * 128 + gc] + bh[g * 128 + gc];
        } else if (r < 384) {
            v = bi[256 + (r - 256)];
        } else {
            v = bh[256 + (r - 384)];
        }
        biasP[i] = v;
        return;
    }
    i -= 1024;
    if (i < NN * HH) {
        float v = x[i];
        unsigned short b = f2b(v);
        xb[i] = b;
        hbA[i] = b;
        out[i] = v;
        return;
    }
    i -= NN * HH;
    if (i < 128) {      // zero row NN of hbA/hbB (gather's masked-lane target)
        hbA[(size_t)NN * 128 + i] = 0;
        hbB[(size_t)NN * 128 + i] = 0;
    }
}

// ================= fused step kernel: R10 structure + optimized gather =================
// LDS 64KB: S[64][256]@0 (32KB) | X[64][128]@16384 (16KB) | H@24576 (16KB)
//           I[64][128]@0 overlays dead S. All GEMM B-operands inline FL from L2.
template<int L>
__global__ __launch_bounds__(512, 4)
void step_kernel(const unsigned int* __restrict__ degP,
                 const unsigned short* __restrict__ rowsT,
                 const unsigned short* __restrict__ hb,
                 const unsigned short* __restrict__ xb,
                 const unsigned short* __restrict__ BmFL,
                 const float* __restrict__ mb,
                 const unsigned short* __restrict__ WrzFL,
                 const unsigned short* __restrict__ WxnFL,
                 const unsigned short* __restrict__ WhnFL,
                 const float* __restrict__ bias,
                 const float* __restrict__ hcur,
                 float* __restrict__ hnext,
                 unsigned short* __restrict__ hbn) {
    constexpr int KCrz = L ? 12 : 8;
    constexpr int KCxn = L ? 8 : 4;
    __shared__ unsigned short lds[32768];
    constexpr int OFF_S = 0, OFF_I = 0, OFF_X = 16384, OFF_H = 24576;

    const int tid = threadIdx.x;
    const int lane = tid & 63;
    const int w = tid >> 6;        // 0..7 = ocg
    const int ln15 = lane & 15;
    const int quad = lane >> 4;
    const int swz = ln15 & 7;
    const int mbase = blockIdx.x * 64;

    // ---- entry: issue X (L1) and H staging; drains under the gather ----
    #pragma unroll
    for (int i = 0; i < 2; ++i) {
        const int r0 = i * 32 + w * 4;
        const int row = r0 + (lane >> 4);
        const int pos = lane & 15;
        int grow = mbase + row;
        if (grow > NN - 1) grow = NN - 1;
        const int sc = (pos & 8) | ((pos & 7) ^ (row & 7));
        const size_t off = (size_t)grow * 128 + sc * 8;
        if (L == 1) gload_lds16(xb + off, &lds[OFF_X + r0 * 128]);
        gload_lds16(hb + off, &lds[OFF_H + r0 * 128]);
    }

    // ---- gather one t-pair into S[64][256]: 4/8-arm batched loads, packed cvt ----
    auto do_gather = [&](int ta) {
        const int tsub = lane >> 5;
        const int t = ta + tsub;
        const int jh = (lane >> 4) & 1;
        const int cl = lane & 15;
        const int cc = cl * 8;
        int node0 = mbase + w * 8 + jh * 4;
        if (node0 > NN - 4) node0 = NN - 4;
        const uint4 dp4 = *(const uint4*)&degP[node0];
        const int tsh = t * 8;
        const size_t rbase = ((size_t)t * NN + node0) * 32;
        const u16x8 ix0 = *(const u16x8*)&rowsT[rbase];
        const u16x8 ix1 = *(const u16x8*)&rowsT[rbase + 32];
        const u16x8 ix2 = *(const u16x8*)&rowsT[rbase + 64];
        const u16x8 ix3 = *(const u16x8*)&rowsT[rbase + 96];
        #pragma unroll
        for (int jj = 0; jj < 4; ++jj) {
            const unsigned int dpw = (jj == 0) ? dp4.x : (jj == 1) ? dp4.y : (jj == 2) ? dp4.z : dp4.w;
            const int m = (int)((dpw >> tsh) & 255u);
            const u16x8 ix = (jj == 0) ? ix0 : (jj == 1) ? ix1 : (jj == 2) ? ix2 : ix3;
            // wave-uniform arm select (branch OUTSIDE the load batch)
            int mm = m;
            mm = max(mm, __shfl_xor(mm, 16, 64));
            mm = max(mm, __shfl_xor(mm, 32, 64));
            const int mms = __builtin_amdgcn_readfirstlane(mm);
            float a[8] = {0.f, 0.f, 0.f, 0.f, 0.f, 0.f, 0.f, 0.f};
            if (mms <= 4) {
                uint4 vv[4];
                #pragma unroll
                for (int q = 0; q < 4; ++q) {
                    unsigned int rowi = (unsigned short)ix[q];
                    if (q >= m) rowi = NN;      // zeroed row
                    vv[q] = *(const uint4*)&hb[(size_t)rowi * 128 + cc];
                }
                #pragma unroll
                for (int q = 0; q < 4; ++q) acc8(a, vv[q]);
            } else {
                uint4 vv[8];
                #pragma unroll
                for (int q = 0; q < 8; ++q) {
                    unsigned int rowi = (unsigned short)ix[q];
                    if (q >= m) rowi = NN;
                    vv[q] = *(const uint4*)&hb[(size_t)rowi * 128 + cc];
                }
                #pragma unroll
                for (int q = 0; q < 8; ++q) acc8(a, vv[q]);
                if (mms > 8) {                  // rare tail (P ~ 0.4%)
                    const unsigned short* rp = &rowsT[rbase + jj * 32];
                    for (int p = 8; p < m; ++p) {
                        const uint4 v = *(const uint4*)&hb[(size_t)rp[p] * 128 + cc];
                        acc8(a, v);
                    }
                }
            }
            const int lrow = w * 8 + jh * 4 + jj;
            const int kg = tsub * 16 + cl;
            const int pos = (kg & ~7) | ((kg & 7) ^ (lrow & 7));
            u16x8 o;
            #pragma unroll
            for (int e = 0; e < 8; ++e) o[e] = f2b(a[e]);
            *(u16x8*)&lds[OFF_S + lrow * 256 + pos * 8] = o;
        }
    };

    f32x4 ainc[4];
    #pragma unroll
    for (int mt = 0; mt < 4; ++mt) ainc[mt] = (f32x4){0.f, 0.f, 0.f, 0.f};

    // ---- inc GEMM: 2 passes, Bm fragments inline from L2 ----
    #pragma unroll
    for (int P = 0; P < 2; ++P) {
        do_gather(P * 2);
        __syncthreads();                       // B1 / B3
        #pragma unroll
        for (int j = 0; j < 8; ++j) {
            const bfrag8 bF = *(const bfrag8*)&BmFL[(size_t)((w * 16 + P * 8 + j) * 64 + lane) * 8];
            const int c = j * 4 + quad;
            const int pos = (c & ~7) | ((c & 7) ^ swz);
            #pragma unroll
            for (int mt = 0; mt < 4; ++mt) {
                const bfrag8 aF = *(const bfrag8*)&lds[OFF_S + (mt * 16 + ln15) * 256 + pos * 8];
                ainc[mt] = __builtin_amdgcn_mfma_f32_16x16x32_bf16(aF, bF, ainc[mt], 0, 0, 0);
            }
        }
        __syncthreads();                       // B2 / B4 (S reads done)
    }

    // ---- inc epilogue: + deg·msg_b -> I tile (overlays S) ----
    {
        const int gc = w * 16 + ln15;
        const float bt0 = mb[gc], bt1 = mb[128 + gc], bt2 = mb[256 + gc], bt3 = mb[384 + gc];
        const int chunk = gc >> 3;
        const int sub = gc & 7;
        #pragma unroll
        for (int mt = 0; mt < 4; ++mt) {
            #pragma unroll
            for (int reg = 0; reg < 4; ++reg) {
                const int lrow = mt * 16 + quad * 4 + reg;
                int row = mbase + lrow;
                if (row > NN - 1) row = NN - 1;
                const unsigned int dp = degP[row];
                const float v = ainc[mt][reg]
                    + (float)(dp & 255u) * bt0 + (float)((dp >> 8) & 255u) * bt1
                    + (float)((dp >> 16) & 255u) * bt2 + (float)((dp >> 24) & 255u) * bt3;
                const int pos = (chunk & 8) | ((chunk & 7) ^ (lrow & 7));
                lds[OFF_I + lrow * 128 + pos * 8 + sub] = f2b(v);
            }
        }
    }
    __syncthreads();                           // B5 (I visible)

    // ---- phase C: rz/xn/hn GEMM stream, W fragments inline from L2, no barriers ----
    f32x4 ar[4], az[4], ax[4], ah[4];
    #pragma unroll
    for (int mt = 0; mt < 4; ++mt) {
        ar[mt] = (f32x4){0.f, 0.f, 0.f, 0.f};
        az[mt] = (f32x4){0.f, 0.f, 0.f, 0.f};
        ax[mt] = (f32x4){0.f, 0.f, 0.f, 0.f};
        ah[mt] = (f32x4){0.f, 0.f, 0.f, 0.f};
    }

    #pragma unroll
    for (int kc = 0; kc < KCrz; ++kc) {
        const int abase = (L == 1) ? (kc < 4 ? OFF_X : (kc < 8 ? OFF_I : OFF_H))
                                   : (kc < 4 ? OFF_I : OFF_H);
        const int c = (kc & 3) * 4 + quad;
        const int pos = (c & 8) | ((c & 7) ^ swz);
        const bfrag8 bR = *(const bfrag8*)&WrzFL[(size_t)((w * KCrz + kc) * 64 + lane) * 8];
        const bfrag8 bZ = *(const bfrag8*)&WrzFL[(size_t)(((w + 8) * KCrz + kc) * 64 + lane) * 8];
        #pragma unroll
        for (int mt = 0; mt < 4; ++mt) {
            const bfrag8 aF = *(const bfrag8*)&lds[abase + (mt * 16 + ln15) * 128 + pos * 8];
            ar[mt] = __builtin_amdgcn_mfma_f32_16x16x32_bf16(aF, bR, ar[mt], 0, 0, 0);
            az[mt] = __builtin_amdgcn_mfma_f32_16x16x32_bf16(aF, bZ, az[mt], 0, 0, 0);
        }
    }
    #pragma unroll
    for (int kc = 0; kc < KCxn; ++kc) {
        const int abase = (L == 1) ? (kc < 4 ? OFF_X : OFF_I) : OFF_I;
        const int c = (kc & 3) * 4 + quad;
        const int pos = (c & 8) | ((c & 7) ^ swz);
        const bfrag8 bX = *(const bfrag8*)&WxnFL[(size_t)((w * KCxn + kc) * 64 + lane) * 8];
        #pragma unroll
        for (int mt = 0; mt < 4; ++mt) {
            const bfrag8 aF = *(const bfrag8*)&lds[abase + (mt * 16 + ln15) * 128 + pos * 8];
            ax[mt] = __builtin_amdgcn_mfma_f32_16x16x32_bf16(aF, bX, ax[mt], 0, 0, 0);
        }
    }
    #pragma unroll
    for (int kc = 0; kc < 4; ++kc) {
        const int c = kc * 4 + quad;
        const int pos = (c & 8) | ((c & 7) ^ swz);
        const bfrag8 bH = *(const bfrag8*)&WhnFL[(size_t)((w * 4 + kc) * 64 + lane) * 8];
        #pragma unroll
        for (int mt = 0; mt < 4; ++mt) {
            const bfrag8 aF = *(const bfrag8*)&lds[OFF_H + (mt * 16 + ln15) * 128 + pos * 8];
            ah[mt] = __builtin_amdgcn_mfma_f32_16x16x32_bf16(aF, bH, ah[mt], 0, 0, 0);
        }
    }

    // ---- GRU gate ----
    {
        const int gc = w * 16 + ln15;
        const float br = bias[gc];
        const float bz = bias[128 + gc];
        const float bxnv = bias[256 + gc];
        const float bhnv = bias[384 + gc];
        #pragma unroll
        for (int mt = 0; mt < 4; ++mt) {
            #pragma unroll
            for (int reg = 0; reg < 4; ++reg) {
                const int row = mbase + mt * 16 + quad * 4 + reg;
                if (row < NN) {
                    const float r = sigm(ar[mt][reg] + br);
                    const float z = sigm(az[mt][reg] + bz);
                    const float n = tanhf(ax[mt][reg] + bxnv + r * (ah[mt][reg] + bhnv));
                    const float h = hcur[(size_t)row * 128 + gc];
                    const float o = (1.f - z) * n + z * h;
                    hnext[(size_t)row * 128 + gc] = o;
                    if (hbn) hbn[(size_t)row * 128 + gc] = f2b(o);
                }
            }
        }
    }
}

extern "C" void kernel_launch(void* const* d_in, const int* in_sizes, int n_in,
                              void* d_out, int out_size, void* d_ws, size_t ws_size,
                              hipStream_t stream) {
    (void)in_sizes; (void)n_in; (void)out_size; (void)ws_size;
    const float* x     = (const float*)d_in[0];
    const int*   edges = (const int*)d_in[1];
    const float* msg_W = (const float*)d_in[2];
    const float* msg_b = (const float*)d_in[3];
    const float* W0ih  = (const float*)d_in[4];
    const float* W0hh  = (const float*)d_in[5];
    const float* b0ih  = (const float*)d_in[6];
    const float* b0hh  = (const float*)d_in[7];
    const float* W1ih  = (const float*)d_in[8];
    const float* W1hh  = (const float*)d_in[9];
    const float* b1ih  = (const float*)d_in[10];
    const float* b1hh  = (const float*)d_in[11];
    float* out = (float*)d_out;

    // ---- workspace layout (float units) ----
    float* ws = (float*)d_ws;
    unsigned short* xb  = (unsigned short*)ws;                    // N*128 u16
    unsigned short* hbA = (unsigned short*)(ws + 3200000);        // (N+1)*128 u16
    unsigned short* hbB = (unsigned short*)(ws + 6400100);
    float* hA           = ws + 9700000;                           // N*128 fp32
    unsigned short* wb  = (unsigned short*)(ws + 16200000);       // 376832 u16
    float* biasP        = ws + 16400000;                          // 1024 fl
    int* degT           = (int*)(ws + 16500000);                  // 4N ints
    unsigned int* degP  = (unsigned int*)(ws + 16750000);         // N u32
    unsigned short* rowsT = (unsigned short*)(ws + 16850000);     // 4N*32 u16

    unsigned short* BmFL   = wb;
    unsigned short* WrzFL0 = wb + 131072;
    unsigned short* WrzFL1 = wb + 196608;
    unsigned short* WxnFL0 = wb + 294912;
    unsigned short* WxnFL1 = wb + 311296;
    unsigned short* WhnFL0 = wb + 344064;
    unsigned short* WhnFL1 = wb + 360448;

    hipMemsetAsync(degT, 0, (size_t)NN * 4 * sizeof(int), stream);
    place_bucket<<<(TT * EE + 255) / 256, 256, 0, stream>>>(edges, degT, rowsT);

    // work items: NN degP + 376832 weights + 1024 bias + NN*HH x + 128 zero = 6827984
    setup_convert<<<26672, 256, 0, stream>>>(msg_W, W0ih, W0hh, W1ih, W1hh,
                                             b0ih, b0hh, b1ih, b1hh, x,
                                             degT, degP, wb, biasP, xb, hbA, hbB, out);

    const int gblocks = (NN + 63) / 64;   // 782
    for (int s = 0; s < 6; ++s) {
        const int l = s / 3;
        const float* hcur  = (s % 2 == 0) ? out : hA;
        float*       hnext = (s % 2 == 0) ? hA : out;
        unsigned short* hbc = (s % 2 == 0) ? hbA : hbB;
        unsigned short* hbn = (s % 2 == 0) ? hbB : hbA;
        if (s == 5) hbn = nullptr;        // last step: bf16 h never consumed

        if (l == 0)
            step_kernel<0><<<gblocks, 512, 0, stream>>>(
                degP, rowsT, hbc, xb, BmFL, msg_b, WrzFL0, WxnFL0, WhnFL0,
                biasP, hcur, hnext, hbn);
        else
            step_kernel<1><<<gblocks, 512, 0, stream>>>(
                degP, rowsT, hbc, xb, BmFL + 65536, msg_b + 512, WrzFL1, WxnFL1, WhnFL1,
                biasP + 512, hcur, hnext, hbn);
    }
    // s=5 (odd) writes hnext=out — final h lands in d_out.
}

// Round 12
// 588.617 us; speedup vs baseline: 1.0715x; 1.0715x over previous
//
#include <hip/hip_runtime.h>
#include <cstddef>

#define NN 50000
#define HH 128
#define TT 4
#define EE 150000

typedef __attribute__((ext_vector_type(8))) short bfrag8;
typedef __attribute__((ext_vector_type(4))) float f32x4;
typedef __attribute__((ext_vector_type(8))) unsigned short u16x8;

__device__ __forceinline__ float sigm(float v) { return 1.0f / (1.0f + __expf(-v)); }

__device__ __forceinline__ unsigned short f2b(float f) {
    unsigned int u = __float_as_uint(f);
    u += 0x7fffu + ((u >> 16) & 1u);
    return (unsigned short)(u >> 16);
}
__device__ __forceinline__ float b2f(unsigned short s) {
    return __uint_as_float(((unsigned int)s) << 16);
}

__device__ __forceinline__ void gload_lds16(const void* gp, void* lp) {
    __builtin_amdgcn_global_load_lds(
        (const __attribute__((address_space(1))) unsigned int*)gp,
        (__attribute__((address_space(3))) unsigned int*)lp, 16, 0, 0);
}

// packed bf16x8 (as uint4) -> 8 f32 accumulate: 2 VALU/elem total
__device__ __forceinline__ void acc8(float* a, uint4 v) {
    a[0] += __uint_as_float(v.x << 16);
    a[1] += __uint_as_float(v.x & 0xffff0000u);
    a[2] += __uint_as_float(v.y << 16);
    a[3] += __uint_as_float(v.y & 0xffff0000u);
    a[4] += __uint_as_float(v.z << 16);
    a[5] += __uint_as_float(v.z & 0xffff0000u);
    a[6] += __uint_as_float(v.w << 16);
    a[7] += __uint_as_float(v.w & 0xffff0000u);
}

// ================= bucket build: t-major per-(t,node) buckets =================
__global__ __launch_bounds__(256)
void place_bucket(const int* __restrict__ edges, int* __restrict__ degT,
                  unsigned short* __restrict__ rowsT) {
    int eg = blockIdx.x * 256 + threadIdx.x;
    if (eg >= TT * EE) return;
    int t = eg / EE;
    int src = edges[eg * 2];
    int tgt = edges[eg * 2 + 1];
    int p = atomicAdd(&degT[t * NN + tgt], 1);
    if (p < 32) rowsT[((size_t)t * NN + tgt) * 32 + p] = (unsigned short)src;
}

// ================= setup: degP pack + FRAGMENT-LINEAR weight layouts =================
// FL(W[OC][K])[ocg][kc][lane][e] = W[ocg*16+(lane&15)][kc*32+(lane>>4)*8+e]
__global__ __launch_bounds__(256)
void setup_convert(const float* __restrict__ msg_W,
                   const float* __restrict__ W0ih, const float* __restrict__ W0hh,
                   const float* __restrict__ W1ih, const float* __restrict__ W1hh,
                   const float* __restrict__ b0ih, const float* __restrict__ b0hh,
                   const float* __restrict__ b1ih, const float* __restrict__ b1hh,
                   const float* __restrict__ x, const int* __restrict__ degT,
                   unsigned int* __restrict__ degP,
                   unsigned short* __restrict__ wb, float* __restrict__ biasP,
                   unsigned short* __restrict__ xb, unsigned short* __restrict__ hbA,
                   unsigned short* __restrict__ hbB, float* __restrict__ out) {
    int i = blockIdx.x * 256 + threadIdx.x;
    if (i < NN) {
        unsigned int v0 = degT[i];            if (v0 > 32) v0 = 32;
        unsigned int v1 = degT[NN + i];       if (v1 > 32) v1 = 32;
        unsigned int v2 = degT[2 * NN + i];   if (v2 > 32) v2 = 32;
        unsigned int v3 = degT[3 * NN + i];   if (v3 > 32) v3 = 32;
        degP[i] = v0 | (v1 << 8) | (v2 << 16) | (v3 << 24);
        return;
    }
    i -= NN;
    if (i < 131072) {   // BmFL [2][8 ocg][16 kc][64][8]; k = t*128+h
        int l = i >> 16, r = i & 65535;
        int e = r & 7, lane = (r >> 3) & 63, kc = (r >> 9) & 15, ocg = (r >> 13) & 7;
        int f = ocg * 16 + (lane & 15);
        int k = kc * 32 + (lane >> 4) * 8 + e;
        int t = k >> 7, h = k & 127;
        wb[i] = f2b(msg_W[l * 65536 + t * 16384 + f * 128 + h]);
        return;
    }
    i -= 131072;
    if (i < 65536) {    // WrzFL0 [16 ocg][8 kc][64][8]; ocg<8 r else z; k<128 Wih else Whh
        int e = i & 7, lane = (i >> 3) & 63, kc = (i >> 9) & 7, ocg = (i >> 12) & 15;
        int p = ocg * 16 + (lane & 15);
        int g = p >> 7, gc = p & 127;
        int k = kc * 32 + (lane >> 4) * 8 + e;
        float v = (k < 128) ? W0ih[(g * 128 + gc) * 128 + k] : W0hh[(g * 128 + gc) * 128 + (k - 128)];
        wb[131072 + i] = f2b(v);
        return;
    }
    i -= 65536;
    if (i < 98304) {    // WrzFL1 [16 ocg][12 kc][64][8]; k<256 Wih else Whh
        int e = i & 7, lane = (i >> 3) & 63, rem = i >> 9;
        int kc = rem % 12, ocg = rem / 12;
        int p = ocg * 16 + (lane & 15);
        int g = p >> 7, gc = p & 127;
        int k = kc * 32 + (lane >> 4) * 8 + e;
        float v = (k < 256) ? W1ih[(g * 128 + gc) * 256 + k] : W1hh[(g * 128 + gc) * 128 + (k - 256)];
        wb[196608 + i] = f2b(v);
        return;
    }
    i -= 98304;
    if (i < 16384) {    // WxnFL0 [8][4][64][8]
        int e = i & 7, lane = (i >> 3) & 63, rem = i >> 9;
        int kc = rem & 3, ocg = rem >> 2;
        int gc = ocg * 16 + (lane & 15);
        int k = kc * 32 + (lane >> 4) * 8 + e;
        wb[294912 + i] = f2b(W0ih[(256 + gc) * 128 + k]);
        return;
    }
    i -= 16384;
    if (i < 32768) {    // WxnFL1 [8][8][64][8]
        int e = i & 7, lane = (i >> 3) & 63;
        int kc = (i >> 9) & 7, ocg = (i >> 12) & 7;
        int gc = ocg * 16 + (lane & 15);
        int k = kc * 32 + (lane >> 4) * 8 + e;
        wb[311296 + i] = f2b(W1ih[(256 + gc) * 256 + k]);
        return;
    }
    i -= 32768;
    if (i < 16384) {    // WhnFL0 [8][4][64][8]
        int e = i & 7, lane = (i >> 3) & 63, rem = i >> 9;
        int kc = rem & 3, ocg = rem >> 2;
        int gc = ocg * 16 + (lane & 15);
        int k = kc * 32 + (lane >> 4) * 8 + e;
        wb[344064 + i] = f2b(W0hh[(256 + gc) * 128 + k]);
        return;
    }
    i -= 16384;
    if (i < 16384) {    // WhnFL1 [8][4][64][8]
        int e = i & 7, lane = (i >> 3) & 63, rem = i >> 9;
        int kc = rem & 3, ocg = rem >> 2;
        int gc = ocg * 16 + (lane & 15);
        int k = kc * 32 + (lane >> 4) * 8 + e;
        wb[360448 + i] = f2b(W1hh[(256 + gc) * 128 + k]);
        return;
    }
    i -= 16384;
    if (i < 1024) {     // bias [2][512]
        int l = i >> 9, r = i & 511;
        const float* bi = l ? b1ih : b0ih;
        const float* bh = l ? b1hh : b0hh;
        float v;
        if (r < 256) {
            int g = r >> 7, gc = r & 127;
            v = bi[g * 128 + gc] + bh[g * 128 + gc];
        } else if (r < 384) {
            v = bi[256 + (r - 256)];
        } else {
            v = bh[256 + (r - 384)];
        }
        biasP[i] = v;
        return;
    }
    i -= 1024;
    if (i < NN * HH) {
        float v = x[i];
        unsigned short b = f2b(v);
        xb[i] = b;
        hbA[i] = b;
        out[i] = v;
        return;
    }
    i -= NN * HH;
    if (i < 128) {      // zero row NN of hbA/hbB (gather's masked-lane target)
        hbA[(size_t)NN * 128 + i] = 0;
        hbB[(size_t)NN * 128 + i] = 0;
    }
}

// ================= fused step kernel: R10 structure + packed-cvt gather =================
// LDS 64KB: S[64][256]@0 (32KB) | X[64][128]@16384 (16KB) | H@24576 (16KB)
//           I[64][128]@0 overlays dead S. All GEMM B-operands inline FL from L2.
template<int L>
__global__ __launch_bounds__(512, 4)
void step_kernel(const unsigned int* __restrict__ degP,
                 const unsigned short* __restrict__ rowsT,
                 const unsigned short* __restrict__ hb,
                 const unsigned short* __restrict__ xb,
                 const unsigned short* __restrict__ BmFL,
                 const float* __restrict__ mb,
                 const unsigned short* __restrict__ WrzFL,
                 const unsigned short* __restrict__ WxnFL,
                 const unsigned short* __restrict__ WhnFL,
                 const float* __restrict__ bias,
                 const float* __restrict__ hcur,
                 float* __restrict__ hnext,
                 unsigned short* __restrict__ hbn) {
    constexpr int KCrz = L ? 12 : 8;
    constexpr int KCxn = L ? 8 : 4;
    __shared__ unsigned short lds[32768];
    constexpr int OFF_S = 0, OFF_I = 0, OFF_X = 16384, OFF_H = 24576;

    const int tid = threadIdx.x;
    const int lane = tid & 63;
    const int w = tid >> 6;        // 0..7 = ocg
    const int ln15 = lane & 15;
    const int quad = lane >> 4;
    const int swz = ln15 & 7;
    const int mbase = blockIdx.x * 64;

    // ---- entry: issue X (L1) and H staging; drains under the gather ----
    #pragma unroll
    for (int i = 0; i < 2; ++i) {
        const int r0 = i * 32 + w * 4;
        const int row = r0 + (lane >> 4);
        const int pos = lane & 15;
        int grow = mbase + row;
        if (grow > NN - 1) grow = NN - 1;
        const int sc = (pos & 8) | ((pos & 7) ^ (row & 7));
        const size_t off = (size_t)grow * 128 + sc * 8;
        if (L == 1) gload_lds16(xb + off, &lds[OFF_X + r0 * 128]);
        gload_lds16(hb + off, &lds[OFF_H + r0 * 128]);
    }

    // ---- gather one t-pair into S[64][256]: R10 loop shape, packed conversion ----
    auto do_gather = [&](int ta) {
        const int tsub = lane >> 5;
        const int t = ta + tsub;
        const int jh = (lane >> 4) & 1;
        const int cl = lane & 15;
        const int cc = cl * 8;
        int node0 = mbase + w * 8 + jh * 4;
        if (node0 > NN - 4) node0 = NN - 4;
        const uint4 dp4 = *(const uint4*)&degP[node0];
        const int tsh = t * 8;
        const size_t rbase = ((size_t)t * NN + node0) * 32;
        const u16x8 ix0 = *(const u16x8*)&rowsT[rbase];
        const u16x8 ix1 = *(const u16x8*)&rowsT[rbase + 32];
        const u16x8 ix2 = *(const u16x8*)&rowsT[rbase + 64];
        const u16x8 ix3 = *(const u16x8*)&rowsT[rbase + 96];
        #pragma unroll
        for (int jj = 0; jj < 4; ++jj) {
            const unsigned int dpw = (jj == 0) ? dp4.x : (jj == 1) ? dp4.y : (jj == 2) ? dp4.z : dp4.w;
            const int m = (int)((dpw >> tsh) & 255u);
            const u16x8 ix = (jj == 0) ? ix0 : (jj == 1) ? ix1 : (jj == 2) ? ix2 : ix3;
            float a[8] = {0.f, 0.f, 0.f, 0.f, 0.f, 0.f, 0.f, 0.f};
            #pragma unroll
            for (int q = 0; q < 8; ++q) {
                unsigned int rowi = (unsigned short)ix[q];
                if (q >= m) rowi = NN;      // zeroed row (hot in cache)
                const uint4 v = *(const uint4*)&hb[(size_t)rowi * 128 + cc];
                acc8(a, v);
            }
            if (m > 8) {                    // rare tail (P ~ 0.4%)
                const unsigned short* rp = &rowsT[rbase + jj * 32];
                for (int p = 8; p < m; ++p) {
                    const uint4 v = *(const uint4*)&hb[(size_t)rp[p] * 128 + cc];
                    acc8(a, v);
                }
            }
            const int lrow = w * 8 + jh * 4 + jj;
            const int kg = tsub * 16 + cl;
            const int pos = (kg & ~7) | ((kg & 7) ^ (lrow & 7));
            u16x8 o;
            #pragma unroll
            for (int e = 0; e < 8; ++e) o[e] = f2b(a[e]);
            *(u16x8*)&lds[OFF_S + lrow * 256 + pos * 8] = o;
        }
    };

    f32x4 ainc[4];
    #pragma unroll
    for (int mt = 0; mt < 4; ++mt) ainc[mt] = (f32x4){0.f, 0.f, 0.f, 0.f};

    // ---- inc GEMM: 2 passes, Bm fragments inline from L2 ----
    #pragma unroll
    for (int P = 0; P < 2; ++P) {
        do_gather(P * 2);
        __syncthreads();                       // B1 / B3
        #pragma unroll
        for (int j = 0; j < 8; ++j) {
            const bfrag8 bF = *(const bfrag8*)&BmFL[(size_t)((w * 16 + P * 8 + j) * 64 + lane) * 8];
            const int c = j * 4 + quad;
            const int pos = (c & ~7) | ((c & 7) ^ swz);
            #pragma unroll
            for (int mt = 0; mt < 4; ++mt) {
                const bfrag8 aF = *(const bfrag8*)&lds[OFF_S + (mt * 16 + ln15) * 256 + pos * 8];
                ainc[mt] = __builtin_amdgcn_mfma_f32_16x16x32_bf16(aF, bF, ainc[mt], 0, 0, 0);
            }
        }
        __syncthreads();                       // B2 / B4 (S reads done)
    }

    // ---- inc epilogue: + deg·msg_b -> I tile (overlays S) ----
    {
        const int gc = w * 16 + ln15;
        const float bt0 = mb[gc], bt1 = mb[128 + gc], bt2 = mb[256 + gc], bt3 = mb[384 + gc];
        const int chunk = gc >> 3;
        const int sub = gc & 7;
        #pragma unroll
        for (int mt = 0; mt < 4; ++mt) {
            #pragma unroll
            for (int reg = 0; reg < 4; ++reg) {
                const int lrow = mt * 16 + quad * 4 + reg;
                int row = mbase + lrow;
                if (row > NN - 1) row = NN - 1;
                const unsigned int dp = degP[row];
                const float v = ainc[mt][reg]
                    + (float)(dp & 255u) * bt0 + (float)((dp >> 8) & 255u) * bt1
                    + (float)((dp >> 16) & 255u) * bt2 + (float)((dp >> 24) & 255u) * bt3;
                const int pos = (chunk & 8) | ((chunk & 7) ^ (lrow & 7));
                lds[OFF_I + lrow * 128 + pos * 8 + sub] = f2b(v);
            }
        }
    }
    __syncthreads();                           // B5 (I visible)

    // ---- phase C: rz/xn/hn GEMM stream, W fragments inline from L2, no barriers ----
    f32x4 ar[4], az[4], ax[4], ah[4];
    #pragma unroll
    for (int mt = 0; mt < 4; ++mt) {
        ar[mt] = (f32x4){0.f, 0.f, 0.f, 0.f};
        az[mt] = (f32x4){0.f, 0.f, 0.f, 0.f};
        ax[mt] = (f32x4){0.f, 0.f, 0.f, 0.f};
        ah[mt] = (f32x4){0.f, 0.f, 0.f, 0.f};
    }

    #pragma unroll
    for (int kc = 0; kc < KCrz; ++kc) {
        const int abase = (L == 1) ? (kc < 4 ? OFF_X : (kc < 8 ? OFF_I : OFF_H))
                                   : (kc < 4 ? OFF_I : OFF_H);
        const int c = (kc & 3) * 4 + quad;
        const int pos = (c & 8) | ((c & 7) ^ swz);
        const bfrag8 bR = *(const bfrag8*)&WrzFL[(size_t)((w * KCrz + kc) * 64 + lane) * 8];
        const bfrag8 bZ = *(const bfrag8*)&WrzFL[(size_t)(((w + 8) * KCrz + kc) * 64 + lane) * 8];
        #pragma unroll
        for (int mt = 0; mt < 4; ++mt) {
            const bfrag8 aF = *(const bfrag8*)&lds[abase + (mt * 16 + ln15) * 128 + pos * 8];
            ar[mt] = __builtin_amdgcn_mfma_f32_16x16x32_bf16(aF, bR, ar[mt], 0, 0, 0);
            az[mt] = __builtin_amdgcn_mfma_f32_16x16x32_bf16(aF, bZ, az[mt], 0, 0, 0);
        }
    }
    #pragma unroll
    for (int kc = 0; kc < KCxn; ++kc) {
        const int abase = (L == 1) ? (kc < 4 ? OFF_X : OFF_I) : OFF_I;
        const int c = (kc & 3) * 4 + quad;
        const int pos = (c & 8) | ((c & 7) ^ swz);
        const bfrag8 bX = *(const bfrag8*)&WxnFL[(size_t)((w * KCxn + kc) * 64 + lane) * 8];
        #pragma unroll
        for (int mt = 0; mt < 4; ++mt) {
            const bfrag8 aF = *(const bfrag8*)&lds[abase + (mt * 16 + ln15) * 128 + pos * 8];
            ax[mt] = __builtin_amdgcn_mfma_f32_16x16x32_bf16(aF, bX, ax[mt], 0, 0, 0);
        }
    }
    #pragma unroll
    for (int kc = 0; kc < 4; ++kc) {
        const int c = kc * 4 + quad;
        const int pos = (c & 8) | ((c & 7) ^ swz);
        const bfrag8 bH = *(const bfrag8*)&WhnFL[(size_t)((w * 4 + kc) * 64 + lane) * 8];
        #pragma unroll
        for (int mt = 0; mt < 4; ++mt) {
            const bfrag8 aF = *(const bfrag8*)&lds[OFF_H + (mt * 16 + ln15) * 128 + pos * 8];
            ah[mt] = __builtin_amdgcn_mfma_f32_16x16x32_bf16(aF, bH, ah[mt], 0, 0, 0);
        }
    }

    // ---- GRU gate ----
    {
        const int gc = w * 16 + ln15;
        const float br = bias[gc];
        const float bz = bias[128 + gc];
        const float bxnv = bias[256 + gc];
        const float bhnv = bias[384 + gc];
        #pragma unroll
        for (int mt = 0; mt < 4; ++mt) {
            #pragma unroll
            for (int reg = 0; reg < 4; ++reg) {
                const int row = mbase + mt * 16 + quad * 4 + reg;
                if (row < NN) {
                    const float r = sigm(ar[mt][reg] + br);
                    const float z = sigm(az[mt][reg] + bz);
                    const float n = tanhf(ax[mt][reg] + bxnv + r * (ah[mt][reg] + bhnv));
                    const float h = hcur[(size_t)row * 128 + gc];
                    const float o = (1.f - z) * n + z * h;
                    hnext[(size_t)row * 128 + gc] = o;
                    if (hbn) hbn[(size_t)row * 128 + gc] = f2b(o);
                }
            }
        }
    }
}

extern "C" void kernel_launch(void* const* d_in, const int* in_sizes, int n_in,
                              void* d_out, int out_size, void* d_ws, size_t ws_size,
                              hipStream_t stream) {
    (void)in_sizes; (void)n_in; (void)out_size; (void)ws_size;
    const float* x     = (const float*)d_in[0];
    const int*   edges = (const int*)d_in[1];
    const float* msg_W = (const float*)d_in[2];
    const float* msg_b = (const float*)d_in[3];
    const float* W0ih  = (const float*)d_in[4];
    const float* W0hh  = (const float*)d_in[5];
    const float* b0ih  = (const float*)d_in[6];
    const float* b0hh  = (const float*)d_in[7];
    const float* W1ih  = (const float*)d_in[8];
    const float* W1hh  = (const float*)d_in[9];
    const float* b1ih  = (const float*)d_in[10];
    const float* b1hh  = (const float*)d_in[11];
    float* out = (float*)d_out;

    // ---- workspace layout (float units) ----
    float* ws = (float*)d_ws;
    unsigned short* xb  = (unsigned short*)ws;                    // N*128 u16
    unsigned short* hbA = (unsigned short*)(ws + 3200000);        // (N+1)*128 u16
    unsigned short* hbB = (unsigned short*)(ws + 6400100);
    float* hA           = ws + 9700000;                           // N*128 fp32
    unsigned short* wb  = (unsigned short*)(ws + 16200000);       // 376832 u16
    float* biasP        = ws + 16400000;                          // 1024 fl
    int* degT           = (int*)(ws + 16500000);                  // 4N ints
    unsigned int* degP  = (unsigned int*)(ws + 16750000);         // N u32
    unsigned short* rowsT = (unsigned short*)(ws + 16850000);     // 4N*32 u16

    unsigned short* BmFL   = wb;
    unsigned short* WrzFL0 = wb + 131072;
    unsigned short* WrzFL1 = wb + 196608;
    unsigned short* WxnFL0 = wb + 294912;
    unsigned short* WxnFL1 = wb + 311296;
    unsigned short* WhnFL0 = wb + 344064;
    unsigned short* WhnFL1 = wb + 360448;

    hipMemsetAsync(degT, 0, (size_t)NN * 4 * sizeof(int), stream);
    place_bucket<<<(TT * EE + 255) / 256, 256, 0, stream>>>(edges, degT, rowsT);

    // work items: NN degP + 376832 weights + 1024 bias + NN*HH x + 128 zero = 6827984
    setup_convert<<<26672, 256, 0, stream>>>(msg_W, W0ih, W0hh, W1ih, W1hh,
                                             b0ih, b0hh, b1ih, b1hh, x,
                                             degT, degP, wb, biasP, xb, hbA, hbB, out);

    const int gblocks = (NN + 63) / 64;   // 782
    for (int s = 0; s < 6; ++s) {
        const int l = s / 3;
        const float* hcur  = (s % 2 == 0) ? out : hA;
        float*       hnext = (s % 2 == 0) ? hA : out;
        unsigned short* hbc = (s % 2 == 0) ? hbA : hbB;
        unsigned short* hbn = (s % 2 == 0) ? hbB : hbA;
        if (s == 5) hbn = nullptr;        // last step: bf16 h never consumed

        if (l == 0)
            step_kernel<0><<<gblocks, 512, 0, stream>>>(
                degP, rowsT, hbc, xb, BmFL, msg_b, WrzFL0, WxnFL0, WhnFL0,
                biasP, hcur, hnext, hbn);
        else
            step_kernel<1><<<gblocks, 512, 0, stream>>>(
                degP, rowsT, hbc, xb, BmFL + 65536, msg_b + 512, WrzFL1, WxnFL1, WhnFL1,
                biasP + 512, hcur, hnext, hbn);
    }
    // s=5 (odd) writes hnext=out — final h lands in d_out.
}

// Round 13
// 560.300 us; speedup vs baseline: 1.1257x; 1.0505x over previous
//
#include <hip/hip_runtime.h>
#include <cstddef>

#define NN 50000
#define HH 128
#define TT 4
#define EE 150000

typedef __attribute__((ext_vector_type(8))) short bfrag8;
typedef __attribute__((ext_vector_type(4))) float f32x4;
typedef __attribute__((ext_vector_type(8))) unsigned short u16x8;

__device__ __forceinline__ float sigm(float v) { return 1.0f / (1.0f + __expf(-v)); }

__device__ __forceinline__ unsigned short f2b(float f) {
    unsigned int u = __float_as_uint(f);
    u += 0x7fffu + ((u >> 16) & 1u);
    return (unsigned short)(u >> 16);
}
__device__ __forceinline__ float b2f(unsigned short s) {
    return __uint_as_float(((unsigned int)s) << 16);
}

__device__ __forceinline__ void gload_lds16(const void* gp, void* lp) {
    __builtin_amdgcn_global_load_lds(
        (const __attribute__((address_space(1))) unsigned int*)gp,
        (__attribute__((address_space(3))) unsigned int*)lp, 16, 0, 0);
}

// packed bf16x8 (as uint4) -> 8 f32 accumulate: 2 VALU/elem total
__device__ __forceinline__ void acc8(float* a, uint4 v) {
    a[0] += __uint_as_float(v.x << 16);
    a[1] += __uint_as_float(v.x & 0xffff0000u);
    a[2] += __uint_as_float(v.y << 16);
    a[3] += __uint_as_float(v.y & 0xffff0000u);
    a[4] += __uint_as_float(v.z << 16);
    a[5] += __uint_as_float(v.z & 0xffff0000u);
    a[6] += __uint_as_float(v.w << 16);
    a[7] += __uint_as_float(v.w & 0xffff0000u);
}

// ================= bucket build: t-major per-(t,node) buckets =================
__global__ __launch_bounds__(256)
void place_bucket(const int* __restrict__ edges, int* __restrict__ degT,
                  unsigned short* __restrict__ rowsT) {
    int eg = blockIdx.x * 256 + threadIdx.x;
    if (eg >= TT * EE) return;
    int t = eg / EE;
    int src = edges[eg * 2];
    int tgt = edges[eg * 2 + 1];
    int p = atomicAdd(&degT[t * NN + tgt], 1);
    if (p < 32) rowsT[((size_t)t * NN + tgt) * 32 + p] = (unsigned short)src;
}

// ================= setup: degP pack + FRAGMENT-LINEAR weight layouts =================
// FL(W[OC][K])[ocg][kc][lane][e] = W[ocg*16+(lane&15)][kc*32+(lane>>4)*8+e]
__global__ __launch_bounds__(256)
void setup_convert(const float* __restrict__ msg_W,
                   const float* __restrict__ W0ih, const float* __restrict__ W0hh,
                   const float* __restrict__ W1ih, const float* __restrict__ W1hh,
                   const float* __restrict__ b0ih, const float* __restrict__ b0hh,
                   const float* __restrict__ b1ih, const float* __restrict__ b1hh,
                   const float* __restrict__ x, const int* __restrict__ degT,
                   unsigned int* __restrict__ degP,
                   unsigned short* __restrict__ wb, float* __restrict__ biasP,
                   unsigned short* __restrict__ xb, unsigned short* __restrict__ hbA,
                   unsigned short* __restrict__ hbB) {
    int i = blockIdx.x * 256 + threadIdx.x;
    if (i < NN) {
        unsigned int v0 = degT[i];            if (v0 > 32) v0 = 32;
        unsigned int v1 = degT[NN + i];       if (v1 > 32) v1 = 32;
        unsigned int v2 = degT[2 * NN + i];   if (v2 > 32) v2 = 32;
        unsigned int v3 = degT[3 * NN + i];   if (v3 > 32) v3 = 32;
        degP[i] = v0 | (v1 << 8) | (v2 << 16) | (v3 << 24);
        return;
    }
    i -= NN;
    if (i < 131072) {   // BmFL [2][8 ocg][16 kc][64][8]; k = t*128+h
        int l = i >> 16, r = i & 65535;
        int e = r & 7, lane = (r >> 3) & 63, kc = (r >> 9) & 15, ocg = (r >> 13) & 7;
        int f = ocg * 16 + (lane & 15);
        int k = kc * 32 + (lane >> 4) * 8 + e;
        int t = k >> 7, h = k & 127;
        wb[i] = f2b(msg_W[l * 65536 + t * 16384 + f * 128 + h]);
        return;
    }
    i -= 131072;
    if (i < 65536) {    // WrzFL0 [16 ocg][8 kc][64][8]; ocg<8 r else z; k<128 Wih else Whh
        int e = i & 7, lane = (i >> 3) & 63, kc = (i >> 9) & 7, ocg = (i >> 12) & 15;
        int p = ocg * 16 + (lane & 15);
        int g = p >> 7, gc = p & 127;
        int k = kc * 32 + (lane >> 4) * 8 + e;
        float v = (k < 128) ? W0ih[(g * 128 + gc) * 128 + k] : W0hh[(g * 128 + gc) * 128 + (k - 128)];
        wb[131072 + i] = f2b(v);
        return;
    }
    i -= 65536;
    if (i < 98304) {    // WrzFL1 [16 ocg][12 kc][64][8]; k<256 Wih else Whh
        int e = i & 7, lane = (i >> 3) & 63, rem = i >> 9;
        int kc = rem % 12, ocg = rem / 12;
        int p = ocg * 16 + (lane & 15);
        int g = p >> 7, gc = p & 127;
        int k = kc * 32 + (lane >> 4) * 8 + e;
        float v = (k < 256) ? W1ih[(g * 128 + gc) * 256 + k] : W1hh[(g * 128 + gc) * 128 + (k - 256)];
        wb[196608 + i] = f2b(v);
        return;
    }
    i -= 98304;
    if (i < 16384) {    // WxnFL0 [8][4][64][8]
        int e = i & 7, lane = (i >> 3) & 63, rem = i >> 9;
        int kc = rem & 3, ocg = rem >> 2;
        int gc = ocg * 16 + (lane & 15);
        int k = kc * 32 + (lane >> 4) * 8 + e;
        wb[294912 + i] = f2b(W0ih[(256 + gc) * 128 + k]);
        return;
    }
    i -= 16384;
    if (i < 32768) {    // WxnFL1 [8][8][64][8]
        int e = i & 7, lane = (i >> 3) & 63;
        int kc = (i >> 9) & 7, ocg = (i >> 12) & 7;
        int gc = ocg * 16 + (lane & 15);
        int k = kc * 32 + (lane >> 4) * 8 + e;
        wb[311296 + i] = f2b(W1ih[(256 + gc) * 256 + k]);
        return;
    }
    i -= 32768;
    if (i < 16384) {    // WhnFL0 [8][4][64][8]
        int e = i & 7, lane = (i >> 3) & 63, rem = i >> 9;
        int kc = rem & 3, ocg = rem >> 2;
        int gc = ocg * 16 + (lane & 15);
        int k = kc * 32 + (lane >> 4) * 8 + e;
        wb[344064 + i] = f2b(W0hh[(256 + gc) * 128 + k]);
        return;
    }
    i -= 16384;
    if (i < 16384) {    // WhnFL1 [8][4][64][8]
        int e = i & 7, lane = (i >> 3) & 63, rem = i >> 9;
        int kc = rem & 3, ocg = rem >> 2;
        int gc = ocg * 16 + (lane & 15);
        int k = kc * 32 + (lane >> 4) * 8 + e;
        wb[360448 + i] = f2b(W1hh[(256 + gc) * 128 + k]);
        return;
    }
    i -= 16384;
    if (i < 1024) {     // bias [2][512]
        int l = i >> 9, r = i & 511;
        const float* bi = l ? b1ih : b0ih;
        const float* bh = l ? b1hh : b0hh;
        float v;
        if (r < 256) {
            int g = r >> 7, gc = r & 127;
            v = bi[g * 128 + gc] + bh[g * 128 + gc];
        } else if (r < 384) {
            v = bi[256 + (r - 256)];
        } else {
            v = bh[256 + (r - 384)];
        }
        biasP[i] = v;
        return;
    }
    i -= 1024;
    if (i < NN * HH) {
        unsigned short b = f2b(x[i]);
        xb[i] = b;
        hbA[i] = b;
        return;
    }
    i -= NN * HH;
    if (i < 128) {      // zero row NN of hbA/hbB (gather's masked-lane target)
        hbA[(size_t)NN * 128 + i] = 0;
        hbB[(size_t)NN * 128 + i] = 0;
    }
}

// ================= fused step kernel: bf16 h-state (no fp32 h chain) =================
// LDS 64KB: S[64][256]@0 (32KB) | X[64][128]@16384 (16KB) | H@24576 (16KB)
//           I[64][128]@0 overlays dead S. All GEMM B-operands inline FL from L2.
// Gate reads h from the LDS-staged bf16 H tile; writes hbn (bf16) on steps 0..4,
// fp32 out on the final step.
template<int L>
__global__ __launch_bounds__(512, 4)
void step_kernel(const unsigned int* __restrict__ degP,
                 const unsigned short* __restrict__ rowsT,
                 const unsigned short* __restrict__ hb,
                 const unsigned short* __restrict__ xb,
                 const unsigned short* __restrict__ BmFL,
                 const float* __restrict__ mb,
                 const unsigned short* __restrict__ WrzFL,
                 const unsigned short* __restrict__ WxnFL,
                 const unsigned short* __restrict__ WhnFL,
                 const float* __restrict__ bias,
                 unsigned short* __restrict__ hbn,
                 float* __restrict__ outF) {
    constexpr int KCrz = L ? 12 : 8;
    constexpr int KCxn = L ? 8 : 4;
    __shared__ unsigned short lds[32768];
    constexpr int OFF_S = 0, OFF_I = 0, OFF_X = 16384, OFF_H = 24576;

    const int tid = threadIdx.x;
    const int lane = tid & 63;
    const int w = tid >> 6;        // 0..7 = ocg
    const int ln15 = lane & 15;
    const int quad = lane >> 4;
    const int swz = ln15 & 7;
    const int mbase = blockIdx.x * 64;

    // ---- entry: issue X (L1) and H staging; drains under the gather ----
    #pragma unroll
    for (int i = 0; i < 2; ++i) {
        const int r0 = i * 32 + w * 4;
        const int row = r0 + (lane >> 4);
        const int pos = lane & 15;
        int grow = mbase + row;
        if (grow > NN - 1) grow = NN - 1;
        const int sc = (pos & 8) | ((pos & 7) ^ (row & 7));
        const size_t off = (size_t)grow * 128 + sc * 8;
        if (L == 1) gload_lds16(xb + off, &lds[OFF_X + r0 * 128]);
        gload_lds16(hb + off, &lds[OFF_H + r0 * 128]);
    }

    // ---- gather one t-pair into S[64][256]: fixed-trip-8, packed conversion ----
    auto do_gather = [&](int ta) {
        const int tsub = lane >> 5;
        const int t = ta + tsub;
        const int jh = (lane >> 4) & 1;
        const int cl = lane & 15;
        const int cc = cl * 8;
        int node0 = mbase + w * 8 + jh * 4;
        if (node0 > NN - 4) node0 = NN - 4;
        const uint4 dp4 = *(const uint4*)&degP[node0];
        const int tsh = t * 8;
        const size_t rbase = ((size_t)t * NN + node0) * 32;
        const u16x8 ix0 = *(const u16x8*)&rowsT[rbase];
        const u16x8 ix1 = *(const u16x8*)&rowsT[rbase + 32];
        const u16x8 ix2 = *(const u16x8*)&rowsT[rbase + 64];
        const u16x8 ix3 = *(const u16x8*)&rowsT[rbase + 96];
        #pragma unroll
        for (int jj = 0; jj < 4; ++jj) {
            const unsigned int dpw = (jj == 0) ? dp4.x : (jj == 1) ? dp4.y : (jj == 2) ? dp4.z : dp4.w;
            const int m = (int)((dpw >> tsh) & 255u);
            const u16x8 ix = (jj == 0) ? ix0 : (jj == 1) ? ix1 : (jj == 2) ? ix2 : ix3;
            float a[8] = {0.f, 0.f, 0.f, 0.f, 0.f, 0.f, 0.f, 0.f};
            #pragma unroll
            for (int q = 0; q < 8; ++q) {
                unsigned int rowi = (unsigned short)ix[q];
                if (q >= m) rowi = NN;      // zeroed row (hot in cache)
                const uint4 v = *(const uint4*)&hb[(size_t)rowi * 128 + cc];
                acc8(a, v);
            }
            if (m > 8) {                    // rare tail (P ~ 0.4%)
                const unsigned short* rp = &rowsT[rbase + jj * 32];
                for (int p = 8; p < m; ++p) {
                    const uint4 v = *(const uint4*)&hb[(size_t)rp[p] * 128 + cc];
                    acc8(a, v);
                }
            }
            const int lrow = w * 8 + jh * 4 + jj;
            const int kg = tsub * 16 + cl;
            const int pos = (kg & ~7) | ((kg & 7) ^ (lrow & 7));
            u16x8 o;
            #pragma unroll
            for (int e = 0; e < 8; ++e) o[e] = f2b(a[e]);
            *(u16x8*)&lds[OFF_S + lrow * 256 + pos * 8] = o;
        }
    };

    f32x4 ainc[4];
    #pragma unroll
    for (int mt = 0; mt < 4; ++mt) ainc[mt] = (f32x4){0.f, 0.f, 0.f, 0.f};

    // ---- inc GEMM: 2 passes, Bm fragments inline from L2 ----
    #pragma unroll
    for (int P = 0; P < 2; ++P) {
        do_gather(P * 2);
        __syncthreads();                       // B1 / B3
        #pragma unroll
        for (int j = 0; j < 8; ++j) {
            const bfrag8 bF = *(const bfrag8*)&BmFL[(size_t)((w * 16 + P * 8 + j) * 64 + lane) * 8];
            const int c = j * 4 + quad;
            const int pos = (c & ~7) | ((c & 7) ^ swz);
            #pragma unroll
            for (int mt = 0; mt < 4; ++mt) {
                const bfrag8 aF = *(const bfrag8*)&lds[OFF_S + (mt * 16 + ln15) * 256 + pos * 8];
                ainc[mt] = __builtin_amdgcn_mfma_f32_16x16x32_bf16(aF, bF, ainc[mt], 0, 0, 0);
            }
        }
        __syncthreads();                       // B2 / B4 (S reads done)
    }

    // ---- inc epilogue: + deg·msg_b -> I tile (overlays S) ----
    {
        const int gc = w * 16 + ln15;
        const float bt0 = mb[gc], bt1 = mb[128 + gc], bt2 = mb[256 + gc], bt3 = mb[384 + gc];
        const int chunk = gc >> 3;
        const int sub = gc & 7;
        #pragma unroll
        for (int mt = 0; mt < 4; ++mt) {
            #pragma unroll
            for (int reg = 0; reg < 4; ++reg) {
                const int lrow = mt * 16 + quad * 4 + reg;
                int row = mbase + lrow;
                if (row > NN - 1) row = NN - 1;
                const unsigned int dp = degP[row];
                const float v = ainc[mt][reg]
                    + (float)(dp & 255u) * bt0 + (float)((dp >> 8) & 255u) * bt1
                    + (float)((dp >> 16) & 255u) * bt2 + (float)((dp >> 24) & 255u) * bt3;
                const int pos = (chunk & 8) | ((chunk & 7) ^ (lrow & 7));
                lds[OFF_I + lrow * 128 + pos * 8 + sub] = f2b(v);
            }
        }
    }
    __syncthreads();                           // B5 (I visible)

    // ---- phase C: rz/xn/hn GEMM stream, W fragments inline from L2, no barriers ----
    f32x4 ar[4], az[4], ax[4], ah[4];
    #pragma unroll
    for (int mt = 0; mt < 4; ++mt) {
        ar[mt] = (f32x4){0.f, 0.f, 0.f, 0.f};
        az[mt] = (f32x4){0.f, 0.f, 0.f, 0.f};
        ax[mt] = (f32x4){0.f, 0.f, 0.f, 0.f};
        ah[mt] = (f32x4){0.f, 0.f, 0.f, 0.f};
    }

    #pragma unroll
    for (int kc = 0; kc < KCrz; ++kc) {
        const int abase = (L == 1) ? (kc < 4 ? OFF_X : (kc < 8 ? OFF_I : OFF_H))
                                   : (kc < 4 ? OFF_I : OFF_H);
        const int c = (kc & 3) * 4 + quad;
        const int pos = (c & 8) | ((c & 7) ^ swz);
        const bfrag8 bR = *(const bfrag8*)&WrzFL[(size_t)((w * KCrz + kc) * 64 + lane) * 8];
        const bfrag8 bZ = *(const bfrag8*)&WrzFL[(size_t)(((w + 8) * KCrz + kc) * 64 + lane) * 8];
        #pragma unroll
        for (int mt = 0; mt < 4; ++mt) {
            const bfrag8 aF = *(const bfrag8*)&lds[abase + (mt * 16 + ln15) * 128 + pos * 8];
            ar[mt] = __builtin_amdgcn_mfma_f32_16x16x32_bf16(aF, bR, ar[mt], 0, 0, 0);
            az[mt] = __builtin_amdgcn_mfma_f32_16x16x32_bf16(aF, bZ, az[mt], 0, 0, 0);
        }
    }
    #pragma unroll
    for (int kc = 0; kc < KCxn; ++kc) {
        const int abase = (L == 1) ? (kc < 4 ? OFF_X : OFF_I) : OFF_I;
        const int c = (kc & 3) * 4 + quad;
        const int pos = (c & 8) | ((c & 7) ^ swz);
        const bfrag8 bX = *(const bfrag8*)&WxnFL[(size_t)((w * KCxn + kc) * 64 + lane) * 8];
        #pragma unroll
        for (int mt = 0; mt < 4; ++mt) {
            const bfrag8 aF = *(const bfrag8*)&lds[abase + (mt * 16 + ln15) * 128 + pos * 8];
            ax[mt] = __builtin_amdgcn_mfma_f32_16x16x32_bf16(aF, bX, ax[mt], 0, 0, 0);
        }
    }
    #pragma unroll
    for (int kc = 0; kc < 4; ++kc) {
        const int c = kc * 4 + quad;
        const int pos = (c & 8) | ((c & 7) ^ swz);
        const bfrag8 bH = *(const bfrag8*)&WhnFL[(size_t)((w * 4 + kc) * 64 + lane) * 8];
        #pragma unroll
        for (int mt = 0; mt < 4; ++mt) {
            const bfrag8 aF = *(const bfrag8*)&lds[OFF_H + (mt * 16 + ln15) * 128 + pos * 8];
            ah[mt] = __builtin_amdgcn_mfma_f32_16x16x32_bf16(aF, bH, ah[mt], 0, 0, 0);
        }
    }

    // ---- GRU gate: h from LDS H tile (bf16 state) ----
    {
        const int gc = w * 16 + ln15;
        const float br = bias[gc];
        const float bz = bias[128 + gc];
        const float bxnv = bias[256 + gc];
        const float bhnv = bias[384 + gc];
        const int chunk = gc >> 3;
        const int sub = gc & 7;
        #pragma unroll
        for (int mt = 0; mt < 4; ++mt) {
            #pragma unroll
            for (int reg = 0; reg < 4; ++reg) {
                const int lrow = mt * 16 + quad * 4 + reg;
                const int row = mbase + lrow;
                if (row < NN) {
                    const int pos = (chunk & 8) | ((chunk & 7) ^ (lrow & 7));
                    const float h = b2f(lds[OFF_H + lrow * 128 + pos * 8 + sub]);
                    const float r = sigm(ar[mt][reg] + br);
                    const float z = sigm(az[mt][reg] + bz);
                    const float n = tanhf(ax[mt][reg] + bxnv + r * (ah[mt][reg] + bhnv));
                    const float o = (1.f - z) * n + z * h;
                    if (outF) outF[(size_t)row * 128 + gc] = o;
                    else      hbn[(size_t)row * 128 + gc] = f2b(o);
                }
            }
        }
    }
}

extern "C" void kernel_launch(void* const* d_in, const int* in_sizes, int n_in,
                              void* d_out, int out_size, void* d_ws, size_t ws_size,
                              hipStream_t stream) {
    (void)in_sizes; (void)n_in; (void)out_size; (void)ws_size;
    const float* x     = (const float*)d_in[0];
    const int*   edges = (const int*)d_in[1];
    const float* msg_W = (const float*)d_in[2];
    const float* msg_b = (const float*)d_in[3];
    const float* W0ih  = (const float*)d_in[4];
    const float* W0hh  = (const float*)d_in[5];
    const float* b0ih  = (const float*)d_in[6];
    const float* b0hh  = (const float*)d_in[7];
    const float* W1ih  = (const float*)d_in[8];
    const float* W1hh  = (const float*)d_in[9];
    const float* b1ih  = (const float*)d_in[10];
    const float* b1hh  = (const float*)d_in[11];
    float* out = (float*)d_out;

    // ---- workspace layout (float units) ----
    float* ws = (float*)d_ws;
    unsigned short* xb  = (unsigned short*)ws;                    // N*128 u16
    unsigned short* hbA = (unsigned short*)(ws + 3200000);        // (N+1)*128 u16
    unsigned short* hbB = (unsigned short*)(ws + 6400100);
    unsigned short* wb  = (unsigned short*)(ws + 16200000);       // 376832 u16
    float* biasP        = ws + 16400000;                          // 1024 fl
    int* degT           = (int*)(ws + 16500000);                  // 4N ints
    unsigned int* degP  = (unsigned int*)(ws + 16750000);         // N u32
    unsigned short* rowsT = (unsigned short*)(ws + 16850000);     // 4N*32 u16

    unsigned short* BmFL   = wb;
    unsigned short* WrzFL0 = wb + 131072;
    unsigned short* WrzFL1 = wb + 196608;
    unsigned short* WxnFL0 = wb + 294912;
    unsigned short* WxnFL1 = wb + 311296;
    unsigned short* WhnFL0 = wb + 344064;
    unsigned short* WhnFL1 = wb + 360448;

    hipMemsetAsync(degT, 0, (size_t)NN * 4 * sizeof(int), stream);
    place_bucket<<<(TT * EE + 255) / 256, 256, 0, stream>>>(edges, degT, rowsT);

    // work items: NN degP + 376832 weights + 1024 bias + NN*HH x + 128 zero = 6827984
    setup_convert<<<26672, 256, 0, stream>>>(msg_W, W0ih, W0hh, W1ih, W1hh,
                                             b0ih, b0hh, b1ih, b1hh, x,
                                             degT, degP, wb, biasP, xb, hbA, hbB);

    const int gblocks = (NN + 63) / 64;   // 782
    for (int s = 0; s < 6; ++s) {
        const int l = s / 3;
        unsigned short* hbc = (s % 2 == 0) ? hbA : hbB;
        unsigned short* hbn = (s % 2 == 0) ? hbB : hbA;
        float* outF = (s == 5) ? out : nullptr;   // final step writes fp32 out

        if (l == 0)
            step_kernel<0><<<gblocks, 512, 0, stream>>>(
                degP, rowsT, hbc, xb, BmFL, msg_b, WrzFL0, WxnFL0, WhnFL0,
                biasP, hbn, outF);
        else
            step_kernel<1><<<gblocks, 512, 0, stream>>>(
                degP, rowsT, hbc, xb, BmFL + 65536, msg_b + 512, WrzFL1, WxnFL1, WhnFL1,
                biasP + 512, hbn, outF);
    }
    // s=5 writes outF=out — final h lands in d_out.
}